// Round 5
// baseline (410.474 us; speedup 1.0000x reference)
//
#include <hip/hip_runtime.h>
#include <stdint.h>

// LiquidStateMachine on MI355X — round 23.
// r22 post-mortem: R_PB=4/512-block de-convoy REGRESSED (257->351us main):
// halving rows doubled per-CU LDS instr count (same bytes), prologue and
// L2 weight stream — duplication outweighed overlap. r21 wall anatomy:
// 9660 cyc/step = LDS 5500 + VALU 5400 in SERIES (8 waves, 2/SIMD, barrier
// convoy). r23 de-convoys by SPLITTING, not duplicating:
//   1024-thread block, 16 waves. Pair (w, w+8) — same SIMD (simd=w&3) —
//   shares group wg; even wave consumes chunks [0,nh), odd [nh,nit).
//   Per-CU gathers/FMA/L2 traffic IDENTICAL to r21; per-wave chain halves;
//   4 waves/SIMD -> gather||FMA co-residency. Odd writes 8 partials to LDS
//   (conflict-free), even combines + updates (2 barriers/step).
// Prep: r22's fast per-column closed-form fill (proven <<us) ported to the
// 8-cluster/16B-record schedule: bucket k&7, designated cluster (j+ls)&7,
// quota Q=cw/8, overflow->free slots, pads read cluster's shared record.
// Weights EXACT fp32 (r2: rounding flips spikes); f16 spike 0/1 exact.
//
// d_ws layout (bytes):
//   0      PERM[512]  sorted-rank -> column
//   2048   RANK[512]  column -> sorted rank
//   4096   CNT[512]   nnz per column          (zeroed via hipMemsetAsync)
//   8192   CNTW[8]    per-group padded trip count (multiple of 8)
//   8256   IBASE[8]   per-group byte base into IDX region
//   8320   WBASE[8]   per-group byte base into WT region
//   16384  IDX        u16 spike-offset (k<<4):
//                     byte = ib + (j>>3)*1024 + lane*16 + (j&7)*2
//   81920  WT         f32 w: byte = wb + (j>>3)*2048 + lane*32 + (j&7)*4

#define N_NEU 512
#define B_ROWS 2048
#define D_IN 256
#define R_PB 8
#define NBLK (B_ROWS / R_PB)   // 256 blocks x 1024 threads = 1 block/CU

#define WS_PERM    0
#define WS_RANK    2048
#define WS_CNT     4096
#define WS_CNTW    8192
#define WS_IBASE   8256
#define WS_WBASE   8320
#define WS_IDX     16384
#define WS_WT      81920

// spike record: 16 bytes (8 rows x f16 0/1)
#define SPK_OFF(k)  ((k) << 4)
#define SPK_BUF     8192       // one buffer: 512 neurons x 16 B

#define H16_ONE 0x3C00u        // f16 1.0
#define MAXPB   32             // max entries per (column, bucket); mean 6.4

// ---------------------------------------------------------------- prep A
__global__ __launch_bounds__(256) void lsm_count(
    const float* __restrict__ W, uint32_t* __restrict__ ws)
{
    int t  = threadIdx.x;
    int k0 = blockIdx.x * 4;
    int c0 = 0, c1 = 0;
    #pragma unroll
    for (int kk = 0; kk < 4; ++kk) {
        const float* row = W + (size_t)(k0 + kk) * N_NEU;
        c0 += (row[t]       != 0.0f) ? 1 : 0;
        c1 += (row[t + 256] != 0.0f) ? 1 : 0;
    }
    if (c0) atomicAdd(&ws[(WS_CNT >> 2) + t],       (uint32_t)c0);
    if (c1) atomicAdd(&ws[(WS_CNT >> 2) + t + 256], (uint32_t)c1);
}

// ---------------------------------------------------------------- prep B
__global__ __launch_bounds__(512) void lsm_sort(uint32_t* __restrict__ ws)
{
    __shared__ int hist[N_NEU + 1];
    __shared__ int csort[N_NEU];
    __shared__ int gcw[8];

    int t = threadIdx.x;
    int creal = (int)ws[(WS_CNT >> 2) + t];
    for (int i = t; i < N_NEU + 1; i += 512) hist[i] = 0;
    __syncthreads();
    atomicAdd(&hist[creal], 1);
    __syncthreads();
    if (t == 0) {
        int acc = 0;
        for (int v = 0; v <= N_NEU; ++v) { int h = hist[v]; hist[v] = acc; acc += h; }
    }
    __syncthreads();
    int rank = atomicAdd(&hist[creal], 1);
    ws[(WS_PERM >> 2) + rank] = (uint32_t)t;
    ws[(WS_RANK >> 2) + t]    = (uint32_t)rank;
    csort[rank] = creal;
    __syncthreads();
    if (t < 8) {
        int cw = csort[t * 64 + 63];         // ascending -> group max is last
        cw = (cw + 7) & ~7;                  // pad to multiple of 8
        gcw[t] = cw;
        ws[(WS_CNTW >> 2) + t] = (uint32_t)cw;
    }
    __syncthreads();
    if (t == 0) {
        int ai = 0, aw = 0;
        for (int g = 0; g < 8; ++g) {
            ws[(WS_IBASE >> 2) + g] = (uint32_t)ai;
            ws[(WS_WBASE >> 2) + g] = (uint32_t)aw;
            ai += gcw[g] * 64 * 2;           // bytes (u16 per entry)
            aw += gcw[g] * 64 * 4;           // bytes (f32 per entry)
        }
    }
    // fill writes EVERY slot (pads interleaved by the closed-form schedule)
}

// ---------------------------------------------------------------- prep C
// One 64-thread block per COLUMN (512 blocks, full-device parallel).
// Discovery: lane reads k=lane+64i (fixed bucket k&7 = lane&7);
// ballot-compact into per-bucket LDS lists (deterministic, k-ascending).
// Emission (closed-form static schedule, 8 bank clusters of 16B records):
//   slot j: designated cluster b=(j+ls)&7, slot-rank m=j>>3.
//   m <  min(nb,Q): entry (b,m).               [Q = cw/8]
//   else free slot: free rank f (bucket-major) -> overflow entry #f,
//   or pad reading record b (stays in cluster b; broadcast among <=8 lanes).
__global__ __launch_bounds__(64) void lsm_fill(
    const float* __restrict__ W, uint32_t* __restrict__ ws)
{
    int c    = blockIdx.x;
    int lane = threadIdx.x;
    char* base = (char*)ws;

    uint32_t rank = ws[(WS_RANK >> 2) + c];
    int ls = (int)(rank & 63), g = (int)(rank >> 6);
    int cw = (int)ws[(WS_CNTW >> 2) + g];    // multiple of 8, <= 96
    uint32_t ib = ws[(WS_IBASE >> 2) + g];
    uint32_t wb = ws[(WS_WBASE >> 2) + g];

    __shared__ unsigned short ent_k[8][MAXPB];
    __shared__ float          ent_w[8][MAXPB];
    __shared__ int            nb[8];

    int bm = lane & 7;                       // this lane's fixed bucket
    unsigned long long mbk   = 0x0101010101010101ULL << bm;
    unsigned long long below = (1ULL << lane) - 1;
    int myBase = 0;
    for (int i = 0; i < 8; ++i) {
        int k = lane + 64 * i;
        float wv = W[(size_t)k * N_NEU + c];
        bool nz = (wv != 0.0f);
        unsigned long long bal = __ballot(nz);
        if (nz) {
            int p = myBase + __popcll(bal & mbk & below);
            ent_k[bm][p] = (unsigned short)k;
            ent_w[bm][p] = wv;
        }
        myBase += __popcll(bal & mbk);
    }
    if (lane < 8) nb[lane] = myBase;         // 8 lanes/bucket agree on myBase
    __syncthreads();

    int Q = cw >> 3;
    for (int j = lane; j < cw; j += 64) {    // <=2 slots per lane
        int b = (j + ls) & 7;
        int m = j >> 3;
        int nbb = nb[b];
        int d = (nbb < Q) ? nbb : Q;
        unsigned short kk; float wv;
        if (m < d) {
            kk = ent_k[b][m]; wv = ent_w[b][m];
        } else {
            int f = m - d;                   // free rank: bucket-major order
            for (int bp = 0; bp < b; ++bp) {
                int nn = nb[bp];
                f += (Q > nn) ? (Q - nn) : 0;
            }
            int acc = 0, bsel = -1, isel = 0;
            for (int bp = 0; bp < 8; ++bp) {
                int ov = nb[bp] - Q; ov = (ov > 0) ? ov : 0;
                if (bsel < 0 && f < acc + ov) { bsel = bp; isel = Q + (f - acc); }
                acc += ov;
            }
            if (bsel >= 0) { kk = ent_k[bsel][isel]; wv = ent_w[bsel][isel]; }
            else           { kk = (unsigned short)b; wv = 0.0f; }   // pad
        }
        *(unsigned short*)(base + WS_IDX + ib + (j >> 3) * 1024 + ls * 16 + (j & 7) * 2)
            = (unsigned short)SPK_OFF(kk);
        *(float*)(base + WS_WT + wb + (j >> 3) * 2048 + ls * 32 + (j & 7) * 4) = wv;
    }
}

// -------- spill-proof pipeline macros (all scalars, no arrays/fns) --------
// B = spike-buffer base for this step; offsets pre-scaled (k<<4).
#define GATH(P, X, B) \
    P##0 = *(const uint4*)((B) + ((X).x & 0xffffu)); \
    P##1 = *(const uint4*)((B) + ((X).x >> 16));     \
    P##2 = *(const uint4*)((B) + ((X).y & 0xffffu)); \
    P##3 = *(const uint4*)((B) + ((X).y >> 16));     \
    P##4 = *(const uint4*)((B) + ((X).z & 0xffffu)); \
    P##5 = *(const uint4*)((B) + ((X).z >> 16));     \
    P##6 = *(const uint4*)((B) + ((X).w & 0xffffu)); \
    P##7 = *(const uint4*)((B) + ((X).w >> 16));

// mixed-precision FMA: acc(f32) += w(f32) * f16 half of S (lo/hi)
#define FMIX_LO(ACC, WV, S) \
    asm("v_fma_mix_f32 %0, %1, %2, %0 op_sel:[0,0,0] op_sel_hi:[0,1,0]" \
        : "+v"(ACC) : "v"(WV), "v"(S));
#define FMIX_HI(ACC, WV, S) \
    asm("v_fma_mix_f32 %0, %1, %2, %0 op_sel:[0,1,0] op_sel_hi:[0,1,0]" \
        : "+v"(ACC) : "v"(WV), "v"(S));

// one entry: weight WV x 8 rows' f16 spikes (uint4 S = 4 f16-pairs)
#define C1(S, WV) \
    FMIX_LO(rec0, WV, (S).x) FMIX_HI(rec1, WV, (S).x) \
    FMIX_LO(rec2, WV, (S).y) FMIX_HI(rec3, WV, (S).y) \
    FMIX_LO(rec4, WV, (S).z) FMIX_HI(rec5, WV, (S).z) \
    FMIX_LO(rec6, WV, (S).w) FMIX_HI(rec7, WV, (S).w)

#define CONS(P, WA, WB) \
    C1(P##0, (WA).x) C1(P##1, (WA).y) C1(P##2, (WA).z) C1(P##3, (WA).w) \
    C1(P##4, (WB).x) C1(P##5, (WB).y) C1(P##6, (WB).z) C1(P##7, (WB).w)

#define LDW(WA, WB, K) \
    WA = ((const float4*)(wp0 + (K) * 2048))[0]; \
    WB = ((const float4*)(wp0 + (K) * 2048))[1];

// ---------------------------------------------------------------- main
// 1024 threads = 16 waves. Pair (w, w+8) shares SIMD (w&3) and group wg;
// even wave (w<8): chunks [0,nh) + combine + update; odd: chunks [nh,nit)
// + partial write. Per-CU totals identical to r21; per-wave chain halved.
// LDS map (48 KB):
//   [0,8192)        spk buffer 0 (f16 x 8 rows per neuron, 16B)
//   [8192,16384)    spk buffer 1 (ping-pong)
//   [16384,32768)   stg: 16KB scratch — state staging / rates rl / out
//   [32768,49152)   pbuf: 8 groups x 64 cols x 8 rows f32 partials
__global__ __launch_bounds__(1024)
void lsm_main(
    const float* __restrict__ rates, const float* __restrict__ inW,
    const float* __restrict__ vin,   const float* __restrict__ cin,
    const int* __restrict__ nsteps_p,
    const uint32_t* __restrict__ ws, float* __restrict__ out)
{
    __shared__ __align__(16) unsigned char smem[2 * SPK_BUF + 16384 + 16384];
    float* stg  = (float*)(smem + 2 * SPK_BUF);
    float* rl   = stg;
    float* pbuf = (float*)(smem + 2 * SPK_BUF + 16384);

    int q    = threadIdx.x;          // 0..1023
    int blk  = blockIdx.x;
    int r0   = blk * R_PB;
    int w    = q >> 6;               // wave 0..15
    int lane = q & 63;
    int half = w >> 3;               // 0: even (update), 1: odd (partial)
    int wp   = w & 7;                // pair id = SIMD-balanced group slot
    // SIMD balance: waves {s, s+4} (and +8 partners) share SIMD s
    int wg   = (wp < 4) ? wp : (11 - wp);
    int n    = (int)ws[(WS_PERM >> 2) + wg * 64 + lane];
    int cw   = (int)ws[(WS_CNTW >> 2) + wg];     // wave-uniform
    int nit  = cw >> 3;                          // total 8-entry chunks (<=12)
    int nh   = (nit + 1) >> 1;                   // even-wave chunk count
    int nw   = half ? (nit - nh) : nh;           // this wave's chunks (<=6)
    const char* ip0 = (const char*)ws + WS_IDX + ws[(WS_IBASE >> 2) + wg]
                    + lane * 16 + (half ? nh * 1024 : 0);
    const char* wp0 = (const char*)ws + WS_WT  + ws[(WS_WBASE >> 2) + wg]
                    + lane * 32 + (half ? nh * 2048 : 0);
    int spk_n = SPK_OFF(n);                      // this column's record
    float* pb = pbuf + wg * 512 + lane;          // partial slot (8 x stride 64)

    // ---- coalesced state staging: cin then vin through LDS ----
    float c0v[R_PB], v0v[R_PB];
    for (int i = q; i < R_PB * N_NEU; i += 1024)
        stg[i] = cin[(size_t)r0 * N_NEU + i];    // coalesced (rows contiguous)
    __syncthreads();
    if (!half) {
        #pragma unroll
        for (int r = 0; r < R_PB; ++r) c0v[r] = stg[r * N_NEU + n];
    }
    __syncthreads();
    for (int i = q; i < R_PB * N_NEU; i += 1024)
        stg[i] = vin[(size_t)r0 * N_NEU + i];
    __syncthreads();
    if (!half) {
        #pragma unroll
        for (int r = 0; r < R_PB; ++r) v0v[r] = stg[r * N_NEU + n];
    }
    __syncthreads();

    // ---- rates -> rl (coalesced), then I-dot (even waves only) ----
    if (q < (R_PB * D_IN) / 4)
        ((float4*)rl)[q] = ((const float4*)(rates + (size_t)r0 * D_IN))[q];
    __syncthreads();

    float I[R_PB] = {0.f, 0.f, 0.f, 0.f, 0.f, 0.f, 0.f, 0.f};
    if (!half) {
        const float4* wrow = (const float4*)(inW + (size_t)n * D_IN);
        for (int d4 = 0; d4 < D_IN / 4; ++d4) {
            float4 wv = wrow[d4];
            #pragma unroll
            for (int r = 0; r < R_PB; ++r) {
                const float* rr = rl + r * D_IN + d4 * 4;   // LDS broadcast
                I[r] += wv.x * rr[0] + wv.y * rr[1] + wv.z * rr[2] + wv.w * rr[3];
            }
        }
        // initial f16 spikes -> buffer 0
        uint4 sini = make_uint4(0u, 0u, 0u, 0u);
        #pragma unroll
        for (int r = 0; r < R_PB; ++r) {
            unsigned hb = (c0v[r] > 0.f) ? H16_ONE : 0u;
            unsigned sh = (r & 1) ? 16 : 0;
            if (r < 2)      sini.x |= hb << sh;
            else if (r < 4) sini.y |= hb << sh;
            else if (r < 6) sini.z |= hb << sh;
            else            sini.w |= hb << sh;
        }
        *(uint4*)(smem + spk_n) = sini;
    }

    // packed spike counters: byte r = count of (v>0) for row r (<=64, fits)
    unsigned ssx = 0u, ssy = 0u;

    // preload this wave's index stream into registers (constant across steps)
    uint4 xr0, xr1, xr2, xr3, xr4, xr5;
    const uint4 xz = make_uint4(0u, 0u, 0u, 0u);
    xr0 = (0 < nw) ? *(const uint4*)(ip0)        : xz;
    xr1 = (1 < nw) ? *(const uint4*)(ip0 + 1024) : xz;
    xr2 = (2 < nw) ? *(const uint4*)(ip0 + 2048) : xz;
    xr3 = (3 < nw) ? *(const uint4*)(ip0 + 3072) : xz;
    xr4 = (4 < nw) ? *(const uint4*)(ip0 + 4096) : xz;
    xr5 = (5 < nw) ? *(const uint4*)(ip0 + 5120) : xz;

    const float AS   = (float)0.8187307530779818;   // exp(-1/5)
    const float OMAS = (float)(1.0 - 0.8187307530779818);
    const float AM   = (float)0.9512294245007140;   // exp(-1/20)
    const float OMAM = (float)(1.0 - 0.9512294245007140);

    int T = nsteps_p[0];
    __syncthreads();   // initial spikes visible

    #pragma unroll 1
    for (int t = 0; t < T; ++t) {
        const unsigned char* sb = smem + ((t & 1) ? SPK_BUF : 0);   // read buf
        unsigned char*       db = smem + ((t & 1) ? 0 : SPK_BUF);   // write buf

        float rec0 = 0.f, rec1 = 0.f, rec2 = 0.f, rec3 = 0.f;
        float rec4 = 0.f, rec5 = 0.f, rec6 = 0.f, rec7 = 0.f;
        uint4 a0, a1, a2, a3, a4, a5, a6, a7;
        uint4 b0, b1, b2, b3, b4, b5, b6, b7;
        float4 waA, wbA, waB, wbB;

        // 2-deep pipeline over this wave's <=6 chunks
        if (0 < nw) { LDW(waA, wbA, 0)  GATH(a, xr0, sb) }
        if (1 < nw) { LDW(waB, wbB, 1)  GATH(b, xr1, sb) }
        if (0 < nw) { CONS(a, waA, wbA) }
        if (1 < nw) {
            if (2 < nw) { LDW(waA, wbA, 2)  GATH(a, xr2, sb) }
            CONS(b, waB, wbB)
        }
        if (2 < nw) {
            if (3 < nw) { LDW(waB, wbB, 3)  GATH(b, xr3, sb) }
            CONS(a, waA, wbA)
        }
        if (3 < nw) {
            if (4 < nw) { LDW(waA, wbA, 4)  GATH(a, xr4, sb) }
            CONS(b, waB, wbB)
        }
        if (4 < nw) {
            if (5 < nw) { LDW(waB, wbB, 5)  GATH(b, xr5, sb) }
            CONS(a, waA, wbA)
        }
        if (5 < nw) { CONS(b, waB, wbB) }

        // odd wave: publish partials (consecutive lanes -> conflict-free)
        if (half) {
            pb[0]   = rec0; pb[64]  = rec1; pb[128] = rec2; pb[192] = rec3;
            pb[256] = rec4; pb[320] = rec5; pb[384] = rec6; pb[448] = rec7;
        }
        __syncthreads();   // partials visible; all gathers of step t done

        if (!half) {
            rec0 += pb[0];   rec1 += pb[64];  rec2 += pb[128]; rec3 += pb[192];
            rec4 += pb[256]; rec5 += pb[320]; rec6 += pb[384]; rec7 += pb[448];

            uint4 ns = make_uint4(0u, 0u, 0u, 0u);
            unsigned vbx = 0u, vby = 0u;
            {
                float rca[R_PB] = {rec0, rec1, rec2, rec3, rec4, rec5, rec6, rec7};
                #pragma unroll
                for (int r = 0; r < R_PB; ++r) {
                    c0v[r] = AS * c0v[r] + OMAS * (I[r] + rca[r]);
                    v0v[r] = AM * v0v[r] + OMAM * c0v[r];
                    unsigned hb = (c0v[r] > 0.f) ? H16_ONE : 0u;
                    unsigned vb = (v0v[r] > 0.f) ? 1u : 0u;
                    unsigned sh = (r & 1) ? 16 : 0;
                    if (r < 2)      ns.x |= hb << sh;
                    else if (r < 4) ns.y |= hb << sh;
                    else if (r < 6) ns.z |= hb << sh;
                    else            ns.w |= hb << sh;
                    if (r < 4) vbx |= vb << (r * 8);
                    else       vby |= vb << ((r - 4) * 8);
                }
            }
            ssx += vbx;   // bytewise counters, max 64 < 256: no carry
            ssy += vby;
            *(uint4*)(db + spk_n) = ns;
        }
        __syncthreads();   // new spikes visible; old buffer free for reuse
    }

    // ---- coalesced epilogue: stage each quantity through LDS ----
    float invT = 1.0f / (float)T;
    size_t BN = (size_t)B_ROWS * N_NEU;

    if (!half) {
        #pragma unroll
        for (int r = 0; r < R_PB; ++r) {
            unsigned cnt = (r < 4) ? ((ssx >> (r * 8)) & 0xffu)
                                   : ((ssy >> ((r - 4) * 8)) & 0xffu);
            stg[r * N_NEU + n] = (float)cnt * invT;
        }
    }
    __syncthreads();
    for (int i = q; i < R_PB * N_NEU; i += 1024)
        out[(size_t)r0 * N_NEU + i] = stg[i];    // coalesced
    __syncthreads();

    if (!half) {
        #pragma unroll
        for (int r = 0; r < R_PB; ++r) stg[r * N_NEU + n] = v0v[r];
    }
    __syncthreads();
    for (int i = q; i < R_PB * N_NEU; i += 1024)
        out[BN + (size_t)r0 * N_NEU + i] = stg[i];
    __syncthreads();

    if (!half) {
        #pragma unroll
        for (int r = 0; r < R_PB; ++r) stg[r * N_NEU + n] = c0v[r];
    }
    __syncthreads();
    for (int i = q; i < R_PB * N_NEU; i += 1024)
        out[2 * BN + (size_t)r0 * N_NEU + i] = stg[i];
}

// ---------------------------------------------------------------- launch
extern "C" void kernel_launch(void* const* d_in, const int* in_sizes, int n_in,
                              void* d_out, int out_size, void* d_ws, size_t ws_size,
                              hipStream_t stream)
{
    const float* rates = (const float*)d_in[0];
    const float* inW   = (const float*)d_in[1];
    const float* W     = (const float*)d_in[2];
    const float* vin   = (const float*)d_in[3];
    const float* cin   = (const float*)d_in[4];
    const int*   nst   = (const int*)d_in[5];
    uint32_t* ws = (uint32_t*)d_ws;
    float* out = (float*)d_out;
    (void)in_sizes; (void)n_in; (void)out_size; (void)ws_size;

    // zero CNT (harness poisons d_ws to 0xAA before every call)
    hipMemsetAsync((char*)d_ws + WS_CNT, 0, 2048, stream);

    lsm_count<<<128, 256, 0, stream>>>(W, ws);
    lsm_sort<<<1, 512, 0, stream>>>(ws);
    lsm_fill<<<N_NEU, 64, 0, stream>>>(W, ws);
    lsm_main<<<NBLK, 1024, 0, stream>>>(rates, inW, vin, cin, nst, ws, out);
}

// Round 6
// 306.348 us; speedup vs baseline: 1.3399x; 1.3399x over previous
//
#include <hip/hip_runtime.h>
#include <stdint.h>

// LiquidStateMachine on MI355X — round 24.
// r23 post-mortem: 1024-thr block regressed (257->361us main) because the
// compiler allocated VGPR=64 (targeting 2 blocks/CU — useless: grid is 256
// = 1 block/CU) and SPILLED the 2-deep pipeline: WRITE 12->52MB, FETCH
// 8->20MB = scratch traffic. De-convoy theory still untested.
// r24 = r23 fitted to the register budget:
//  (a) __launch_bounds__(1024, 4): 4 waves/SIMD -> 128-VGPR cap.
//  (b) 1-deep pipeline (single gather buffer, JIT weight loads): ~100 live
//      VGPRs. Latency hiding via TLP (4 waves/SIMD, independent progress
//      between barriers) — which IS the de-convoy mechanism under test.
// Per-CU gathers/FMA/traffic identical to r21 (split, not duplicated);
// per-wave chain halved. Everything else byte-identical to r23.
// Weights EXACT fp32 (r2: rounding flips spikes); f16 spike 0/1 exact.
//
// d_ws layout (bytes):
//   0      PERM[512]  sorted-rank -> column
//   2048   RANK[512]  column -> sorted rank
//   4096   CNT[512]   nnz per column          (zeroed via hipMemsetAsync)
//   8192   CNTW[8]    per-group padded trip count (multiple of 8)
//   8256   IBASE[8]   per-group byte base into IDX region
//   8320   WBASE[8]   per-group byte base into WT region
//   16384  IDX        u16 spike-offset (k<<4):
//                     byte = ib + (j>>3)*1024 + lane*16 + (j&7)*2
//   81920  WT         f32 w: byte = wb + (j>>3)*2048 + lane*32 + (j&7)*4

#define N_NEU 512
#define B_ROWS 2048
#define D_IN 256
#define R_PB 8
#define NBLK (B_ROWS / R_PB)   // 256 blocks x 1024 threads = 1 block/CU

#define WS_PERM    0
#define WS_RANK    2048
#define WS_CNT     4096
#define WS_CNTW    8192
#define WS_IBASE   8256
#define WS_WBASE   8320
#define WS_IDX     16384
#define WS_WT      81920

// spike record: 16 bytes (8 rows x f16 0/1)
#define SPK_OFF(k)  ((k) << 4)
#define SPK_BUF     8192       // one buffer: 512 neurons x 16 B

#define H16_ONE 0x3C00u        // f16 1.0
#define MAXPB   32             // max entries per (column, bucket); mean 6.4

// ---------------------------------------------------------------- prep A
__global__ __launch_bounds__(256) void lsm_count(
    const float* __restrict__ W, uint32_t* __restrict__ ws)
{
    int t  = threadIdx.x;
    int k0 = blockIdx.x * 4;
    int c0 = 0, c1 = 0;
    #pragma unroll
    for (int kk = 0; kk < 4; ++kk) {
        const float* row = W + (size_t)(k0 + kk) * N_NEU;
        c0 += (row[t]       != 0.0f) ? 1 : 0;
        c1 += (row[t + 256] != 0.0f) ? 1 : 0;
    }
    if (c0) atomicAdd(&ws[(WS_CNT >> 2) + t],       (uint32_t)c0);
    if (c1) atomicAdd(&ws[(WS_CNT >> 2) + t + 256], (uint32_t)c1);
}

// ---------------------------------------------------------------- prep B
__global__ __launch_bounds__(512) void lsm_sort(uint32_t* __restrict__ ws)
{
    __shared__ int hist[N_NEU + 1];
    __shared__ int csort[N_NEU];
    __shared__ int gcw[8];

    int t = threadIdx.x;
    int creal = (int)ws[(WS_CNT >> 2) + t];
    for (int i = t; i < N_NEU + 1; i += 512) hist[i] = 0;
    __syncthreads();
    atomicAdd(&hist[creal], 1);
    __syncthreads();
    if (t == 0) {
        int acc = 0;
        for (int v = 0; v <= N_NEU; ++v) { int h = hist[v]; hist[v] = acc; acc += h; }
    }
    __syncthreads();
    int rank = atomicAdd(&hist[creal], 1);
    ws[(WS_PERM >> 2) + rank] = (uint32_t)t;
    ws[(WS_RANK >> 2) + t]    = (uint32_t)rank;
    csort[rank] = creal;
    __syncthreads();
    if (t < 8) {
        int cw = csort[t * 64 + 63];         // ascending -> group max is last
        cw = (cw + 7) & ~7;                  // pad to multiple of 8
        gcw[t] = cw;
        ws[(WS_CNTW >> 2) + t] = (uint32_t)cw;
    }
    __syncthreads();
    if (t == 0) {
        int ai = 0, aw = 0;
        for (int g = 0; g < 8; ++g) {
            ws[(WS_IBASE >> 2) + g] = (uint32_t)ai;
            ws[(WS_WBASE >> 2) + g] = (uint32_t)aw;
            ai += gcw[g] * 64 * 2;           // bytes (u16 per entry)
            aw += gcw[g] * 64 * 4;           // bytes (f32 per entry)
        }
    }
    // fill writes EVERY slot (pads interleaved by the closed-form schedule)
}

// ---------------------------------------------------------------- prep C
// One 64-thread block per COLUMN (512 blocks, full-device parallel).
// Discovery: lane reads k=lane+64i (fixed bucket k&7 = lane&7);
// ballot-compact into per-bucket LDS lists (deterministic, k-ascending).
// Emission (closed-form static schedule, 8 bank clusters of 16B records):
//   slot j: designated cluster b=(j+ls)&7, slot-rank m=j>>3.
//   m <  min(nb,Q): entry (b,m).               [Q = cw/8]
//   else free slot: free rank f (bucket-major) -> overflow entry #f,
//   or pad reading record b (stays in cluster b; broadcast among <=8 lanes).
__global__ __launch_bounds__(64) void lsm_fill(
    const float* __restrict__ W, uint32_t* __restrict__ ws)
{
    int c    = blockIdx.x;
    int lane = threadIdx.x;
    char* base = (char*)ws;

    uint32_t rank = ws[(WS_RANK >> 2) + c];
    int ls = (int)(rank & 63), g = (int)(rank >> 6);
    int cw = (int)ws[(WS_CNTW >> 2) + g];    // multiple of 8, <= 96
    uint32_t ib = ws[(WS_IBASE >> 2) + g];
    uint32_t wb = ws[(WS_WBASE >> 2) + g];

    __shared__ unsigned short ent_k[8][MAXPB];
    __shared__ float          ent_w[8][MAXPB];
    __shared__ int            nb[8];

    int bm = lane & 7;                       // this lane's fixed bucket
    unsigned long long mbk   = 0x0101010101010101ULL << bm;
    unsigned long long below = (1ULL << lane) - 1;
    int myBase = 0;
    for (int i = 0; i < 8; ++i) {
        int k = lane + 64 * i;
        float wv = W[(size_t)k * N_NEU + c];
        bool nz = (wv != 0.0f);
        unsigned long long bal = __ballot(nz);
        if (nz) {
            int p = myBase + __popcll(bal & mbk & below);
            ent_k[bm][p] = (unsigned short)k;
            ent_w[bm][p] = wv;
        }
        myBase += __popcll(bal & mbk);
    }
    if (lane < 8) nb[lane] = myBase;         // 8 lanes/bucket agree on myBase
    __syncthreads();

    int Q = cw >> 3;
    for (int j = lane; j < cw; j += 64) {    // <=2 slots per lane
        int b = (j + ls) & 7;
        int m = j >> 3;
        int nbb = nb[b];
        int d = (nbb < Q) ? nbb : Q;
        unsigned short kk; float wv;
        if (m < d) {
            kk = ent_k[b][m]; wv = ent_w[b][m];
        } else {
            int f = m - d;                   // free rank: bucket-major order
            for (int bp = 0; bp < b; ++bp) {
                int nn = nb[bp];
                f += (Q > nn) ? (Q - nn) : 0;
            }
            int acc = 0, bsel = -1, isel = 0;
            for (int bp = 0; bp < 8; ++bp) {
                int ov = nb[bp] - Q; ov = (ov > 0) ? ov : 0;
                if (bsel < 0 && f < acc + ov) { bsel = bp; isel = Q + (f - acc); }
                acc += ov;
            }
            if (bsel >= 0) { kk = ent_k[bsel][isel]; wv = ent_w[bsel][isel]; }
            else           { kk = (unsigned short)b; wv = 0.0f; }   // pad
        }
        *(unsigned short*)(base + WS_IDX + ib + (j >> 3) * 1024 + ls * 16 + (j & 7) * 2)
            = (unsigned short)SPK_OFF(kk);
        *(float*)(base + WS_WT + wb + (j >> 3) * 2048 + ls * 32 + (j & 7) * 4) = wv;
    }
}

// -------- spill-proof pipeline macros (all scalars, no arrays/fns) --------
// B = spike-buffer base for this step; offsets pre-scaled (k<<4).
#define GATH(P, X, B) \
    P##0 = *(const uint4*)((B) + ((X).x & 0xffffu)); \
    P##1 = *(const uint4*)((B) + ((X).x >> 16));     \
    P##2 = *(const uint4*)((B) + ((X).y & 0xffffu)); \
    P##3 = *(const uint4*)((B) + ((X).y >> 16));     \
    P##4 = *(const uint4*)((B) + ((X).z & 0xffffu)); \
    P##5 = *(const uint4*)((B) + ((X).z >> 16));     \
    P##6 = *(const uint4*)((B) + ((X).w & 0xffffu)); \
    P##7 = *(const uint4*)((B) + ((X).w >> 16));

// mixed-precision FMA: acc(f32) += w(f32) * f16 half of S (lo/hi)
#define FMIX_LO(ACC, WV, S) \
    asm("v_fma_mix_f32 %0, %1, %2, %0 op_sel:[0,0,0] op_sel_hi:[0,1,0]" \
        : "+v"(ACC) : "v"(WV), "v"(S));
#define FMIX_HI(ACC, WV, S) \
    asm("v_fma_mix_f32 %0, %1, %2, %0 op_sel:[0,1,0] op_sel_hi:[0,1,0]" \
        : "+v"(ACC) : "v"(WV), "v"(S));

// one entry: weight WV x 8 rows' f16 spikes (uint4 S = 4 f16-pairs)
#define C1(S, WV) \
    FMIX_LO(rec0, WV, (S).x) FMIX_HI(rec1, WV, (S).x) \
    FMIX_LO(rec2, WV, (S).y) FMIX_HI(rec3, WV, (S).y) \
    FMIX_LO(rec4, WV, (S).z) FMIX_HI(rec5, WV, (S).z) \
    FMIX_LO(rec6, WV, (S).w) FMIX_HI(rec7, WV, (S).w)

#define CONS(P, WA, WB) \
    C1(P##0, (WA).x) C1(P##1, (WA).y) C1(P##2, (WA).z) C1(P##3, (WA).w) \
    C1(P##4, (WB).x) C1(P##5, (WB).y) C1(P##6, (WB).z) C1(P##7, (WB).w)

#define LDW(WA, WB, K) \
    WA = ((const float4*)(wp0 + (K) * 2048))[0]; \
    WB = ((const float4*)(wp0 + (K) * 2048))[1];

// one full chunk, 1-deep: weights JIT, gather, consume (reuses a/waA/wbA)
#define CHUNK(K, X) \
    if ((K) < nw) { LDW(waA, wbA, K)  GATH(a, X, sb)  CONS(a, waA, wbA) }

// ---------------------------------------------------------------- main
// 1024 threads = 16 waves. Pair (w, w+8) shares SIMD (w&3) and group wg;
// even wave (w<8): chunks [0,nh) + combine + update; odd: chunks [nh,nit)
// + partial write. Per-CU totals identical to r21; per-wave chain halved.
// TLP (4 waves/SIMD) hides gather latency — the de-convoy mechanism.
// LDS map (48 KB):
//   [0,8192)        spk buffer 0 (f16 x 8 rows per neuron, 16B)
//   [8192,16384)    spk buffer 1 (ping-pong)
//   [16384,32768)   stg: 16KB scratch — state staging / rates rl / out
//   [32768,49152)   pbuf: 8 groups x 64 cols x 8 rows f32 partials
__global__ __launch_bounds__(1024, 4)
void lsm_main(
    const float* __restrict__ rates, const float* __restrict__ inW,
    const float* __restrict__ vin,   const float* __restrict__ cin,
    const int* __restrict__ nsteps_p,
    const uint32_t* __restrict__ ws, float* __restrict__ out)
{
    __shared__ __align__(16) unsigned char smem[2 * SPK_BUF + 16384 + 16384];
    float* stg  = (float*)(smem + 2 * SPK_BUF);
    float* rl   = stg;
    float* pbuf = (float*)(smem + 2 * SPK_BUF + 16384);

    int q    = threadIdx.x;          // 0..1023
    int blk  = blockIdx.x;
    int r0   = blk * R_PB;
    int w    = q >> 6;               // wave 0..15
    int lane = q & 63;
    int half = w >> 3;               // 0: even (update), 1: odd (partial)
    int wp   = w & 7;                // pair id = SIMD-balanced group slot
    // SIMD balance: waves {s, s+4} (and +8 partners) share SIMD s
    int wg   = (wp < 4) ? wp : (11 - wp);
    int n    = (int)ws[(WS_PERM >> 2) + wg * 64 + lane];
    int cw   = (int)ws[(WS_CNTW >> 2) + wg];     // wave-uniform
    int nit  = cw >> 3;                          // total 8-entry chunks (<=12)
    int nh   = (nit + 1) >> 1;                   // even-wave chunk count
    int nw   = half ? (nit - nh) : nh;           // this wave's chunks (<=6)
    const char* ip0 = (const char*)ws + WS_IDX + ws[(WS_IBASE >> 2) + wg]
                    + lane * 16 + (half ? nh * 1024 : 0);
    const char* wp0 = (const char*)ws + WS_WT  + ws[(WS_WBASE >> 2) + wg]
                    + lane * 32 + (half ? nh * 2048 : 0);
    int spk_n = SPK_OFF(n);                      // this column's record
    float* pb = pbuf + wg * 512 + lane;          // partial slot (8 x stride 64)

    // ---- coalesced state staging: cin then vin through LDS ----
    float c0v[R_PB], v0v[R_PB];
    for (int i = q; i < R_PB * N_NEU; i += 1024)
        stg[i] = cin[(size_t)r0 * N_NEU + i];    // coalesced (rows contiguous)
    __syncthreads();
    if (!half) {
        #pragma unroll
        for (int r = 0; r < R_PB; ++r) c0v[r] = stg[r * N_NEU + n];
    }
    __syncthreads();
    for (int i = q; i < R_PB * N_NEU; i += 1024)
        stg[i] = vin[(size_t)r0 * N_NEU + i];
    __syncthreads();
    if (!half) {
        #pragma unroll
        for (int r = 0; r < R_PB; ++r) v0v[r] = stg[r * N_NEU + n];
    }
    __syncthreads();

    // ---- rates -> rl (coalesced), then I-dot (even waves only) ----
    if (q < (R_PB * D_IN) / 4)
        ((float4*)rl)[q] = ((const float4*)(rates + (size_t)r0 * D_IN))[q];
    __syncthreads();

    float I[R_PB] = {0.f, 0.f, 0.f, 0.f, 0.f, 0.f, 0.f, 0.f};
    if (!half) {
        const float4* wrow = (const float4*)(inW + (size_t)n * D_IN);
        for (int d4 = 0; d4 < D_IN / 4; ++d4) {
            float4 wv = wrow[d4];
            #pragma unroll
            for (int r = 0; r < R_PB; ++r) {
                const float* rr = rl + r * D_IN + d4 * 4;   // LDS broadcast
                I[r] += wv.x * rr[0] + wv.y * rr[1] + wv.z * rr[2] + wv.w * rr[3];
            }
        }
        // initial f16 spikes -> buffer 0
        uint4 sini = make_uint4(0u, 0u, 0u, 0u);
        #pragma unroll
        for (int r = 0; r < R_PB; ++r) {
            unsigned hb = (c0v[r] > 0.f) ? H16_ONE : 0u;
            unsigned sh = (r & 1) ? 16 : 0;
            if (r < 2)      sini.x |= hb << sh;
            else if (r < 4) sini.y |= hb << sh;
            else if (r < 6) sini.z |= hb << sh;
            else            sini.w |= hb << sh;
        }
        *(uint4*)(smem + spk_n) = sini;
    }

    // packed spike counters: byte r = count of (v>0) for row r (<=64, fits)
    unsigned ssx = 0u, ssy = 0u;

    // preload this wave's index stream into registers (constant across steps)
    uint4 xr0, xr1, xr2, xr3, xr4, xr5;
    const uint4 xz = make_uint4(0u, 0u, 0u, 0u);
    xr0 = (0 < nw) ? *(const uint4*)(ip0)        : xz;
    xr1 = (1 < nw) ? *(const uint4*)(ip0 + 1024) : xz;
    xr2 = (2 < nw) ? *(const uint4*)(ip0 + 2048) : xz;
    xr3 = (3 < nw) ? *(const uint4*)(ip0 + 3072) : xz;
    xr4 = (4 < nw) ? *(const uint4*)(ip0 + 4096) : xz;
    xr5 = (5 < nw) ? *(const uint4*)(ip0 + 5120) : xz;

    const float AS   = (float)0.8187307530779818;   // exp(-1/5)
    const float OMAS = (float)(1.0 - 0.8187307530779818);
    const float AM   = (float)0.9512294245007140;   // exp(-1/20)
    const float OMAM = (float)(1.0 - 0.9512294245007140);

    int T = nsteps_p[0];
    __syncthreads();   // initial spikes visible

    #pragma unroll 1
    for (int t = 0; t < T; ++t) {
        const unsigned char* sb = smem + ((t & 1) ? SPK_BUF : 0);   // read buf
        unsigned char*       db = smem + ((t & 1) ? 0 : SPK_BUF);   // write buf

        float rec0 = 0.f, rec1 = 0.f, rec2 = 0.f, rec3 = 0.f;
        float rec4 = 0.f, rec5 = 0.f, rec6 = 0.f, rec7 = 0.f;
        uint4 a0, a1, a2, a3, a4, a5, a6, a7;
        float4 waA, wbA;

        // 1-deep: TLP (4 waves/SIMD) hides gather latency
        CHUNK(0, xr0)
        CHUNK(1, xr1)
        CHUNK(2, xr2)
        CHUNK(3, xr3)
        CHUNK(4, xr4)
        CHUNK(5, xr5)

        // odd wave: publish partials (consecutive lanes -> conflict-free)
        if (half) {
            pb[0]   = rec0; pb[64]  = rec1; pb[128] = rec2; pb[192] = rec3;
            pb[256] = rec4; pb[320] = rec5; pb[384] = rec6; pb[448] = rec7;
        }
        __syncthreads();   // partials visible; all gathers of step t done

        if (!half) {
            rec0 += pb[0];   rec1 += pb[64];  rec2 += pb[128]; rec3 += pb[192];
            rec4 += pb[256]; rec5 += pb[320]; rec6 += pb[384]; rec7 += pb[448];

            uint4 ns = make_uint4(0u, 0u, 0u, 0u);
            unsigned vbx = 0u, vby = 0u;
            {
                float rca[R_PB] = {rec0, rec1, rec2, rec3, rec4, rec5, rec6, rec7};
                #pragma unroll
                for (int r = 0; r < R_PB; ++r) {
                    c0v[r] = AS * c0v[r] + OMAS * (I[r] + rca[r]);
                    v0v[r] = AM * v0v[r] + OMAM * c0v[r];
                    unsigned hb = (c0v[r] > 0.f) ? H16_ONE : 0u;
                    unsigned vb = (v0v[r] > 0.f) ? 1u : 0u;
                    unsigned sh = (r & 1) ? 16 : 0;
                    if (r < 2)      ns.x |= hb << sh;
                    else if (r < 4) ns.y |= hb << sh;
                    else if (r < 6) ns.z |= hb << sh;
                    else            ns.w |= hb << sh;
                    if (r < 4) vbx |= vb << (r * 8);
                    else       vby |= vb << ((r - 4) * 8);
                }
            }
            ssx += vbx;   // bytewise counters, max 64 < 256: no carry
            ssy += vby;
            *(uint4*)(db + spk_n) = ns;
        }
        __syncthreads();   // new spikes visible; old buffer free for reuse
    }

    // ---- coalesced epilogue: stage each quantity through LDS ----
    float invT = 1.0f / (float)T;
    size_t BN = (size_t)B_ROWS * N_NEU;

    if (!half) {
        #pragma unroll
        for (int r = 0; r < R_PB; ++r) {
            unsigned cnt = (r < 4) ? ((ssx >> (r * 8)) & 0xffu)
                                   : ((ssy >> ((r - 4) * 8)) & 0xffu);
            stg[r * N_NEU + n] = (float)cnt * invT;
        }
    }
    __syncthreads();
    for (int i = q; i < R_PB * N_NEU; i += 1024)
        out[(size_t)r0 * N_NEU + i] = stg[i];    // coalesced
    __syncthreads();

    if (!half) {
        #pragma unroll
        for (int r = 0; r < R_PB; ++r) stg[r * N_NEU + n] = v0v[r];
    }
    __syncthreads();
    for (int i = q; i < R_PB * N_NEU; i += 1024)
        out[BN + (size_t)r0 * N_NEU + i] = stg[i];
    __syncthreads();

    if (!half) {
        #pragma unroll
        for (int r = 0; r < R_PB; ++r) stg[r * N_NEU + n] = c0v[r];
    }
    __syncthreads();
    for (int i = q; i < R_PB * N_NEU; i += 1024)
        out[2 * BN + (size_t)r0 * N_NEU + i] = stg[i];
}

// ---------------------------------------------------------------- launch
extern "C" void kernel_launch(void* const* d_in, const int* in_sizes, int n_in,
                              void* d_out, int out_size, void* d_ws, size_t ws_size,
                              hipStream_t stream)
{
    const float* rates = (const float*)d_in[0];
    const float* inW   = (const float*)d_in[1];
    const float* W     = (const float*)d_in[2];
    const float* vin   = (const float*)d_in[3];
    const float* cin   = (const float*)d_in[4];
    const int*   nst   = (const int*)d_in[5];
    uint32_t* ws = (uint32_t*)d_ws;
    float* out = (float*)d_out;
    (void)in_sizes; (void)n_in; (void)out_size; (void)ws_size;

    // zero CNT (harness poisons d_ws to 0xAA before every call)
    hipMemsetAsync((char*)d_ws + WS_CNT, 0, 2048, stream);

    lsm_count<<<128, 256, 0, stream>>>(W, ws);
    lsm_sort<<<1, 512, 0, stream>>>(ws);
    lsm_fill<<<N_NEU, 64, 0, stream>>>(W, ws);
    lsm_main<<<NBLK, 1024, 0, stream>>>(rates, inW, vin, cin, nst, ws, out);
}